// Round 7
// baseline (493.046 us; speedup 1.0000x reference)
//
#include <hip/hip_runtime.h>
#include <hip/hip_bf16.h>
#include <hip/hip_cooperative_groups.h>

namespace cg = cooperative_groups;

#define B_    32
#define NBB_  16
#define C_    1024
#define NROI  512
#define KCONV 9216
#define SCALE_ (1.0f/16.0f)
#define EPS_  1e-5f

using f32x4  = __attribute__((ext_vector_type(4))) float;
using bf16x8 = __attribute__((ext_vector_type(8))) short;

__device__ __forceinline__ unsigned f2bf(float f) {
  union { float f; unsigned u; } x; x.f = f;
  unsigned r = x.u + 0x7fffu + ((x.u >> 16) & 1u);   // RNE
  return r >> 16;
}

__device__ __forceinline__ unsigned pk_bf16(float lo, float hi) {
  __hip_bfloat162 h = __float22bfloat162_rn(make_float2(lo, hi));
  return *reinterpret_cast<unsigned*>(&h);
}

__device__ __forceinline__ float hat_int(float t) {
  t = fminf(fmaxf(t, -1.f), 1.f);
  return t + 0.5f - 0.5f * t * fabsf(t);
}

__device__ __forceinline__ void glds16(const void* g, void* l) {
  __builtin_amdgcn_global_load_lds((const __attribute__((address_space(1))) void*)g,
                                   (__attribute__((address_space(3))) void*)l, 16, 0, 0);
}

// ================ K1: ALL preprocessing in one launch.
// blocks [0,32): ROI weights -> W2d ; [32,2080): feat->bf16 featB ;
// [2080,3104): conv_w transpose+cvt -> Wfb ; [3104,3616): w1/w2/w3 cvt.
__global__ __launch_bounds__(256) void prep_all(
    const float* __restrict__ bbox, const float* __restrict__ feat,
    const float* __restrict__ conv_w,
    const float* __restrict__ w1, const float* __restrict__ w2, const float* __restrict__ w3,
    unsigned short* __restrict__ W2d, unsigned short* __restrict__ featB,
    unsigned short* __restrict__ Wfb,
    unsigned short* __restrict__ o1, unsigned short* __restrict__ o2,
    unsigned short* __restrict__ o3)
{
  __shared__ __align__(16) char psm[18504];
  int tid = threadIdx.x;
  int bx = blockIdx.x;

  if (bx < 32) {                       // ---- prep_w2d, b = bx
    int b = bx;
    float* wyS = (float*)psm;          // 1056 f32
    float* wxS = wyS + 1056;           // 1056 f32
    for (int t = tid; t < 352; t += 256) {
      int n = t / 22, i = t - n * 22;
      float4 bb = ((const float4*)bbox)[b*16 + n];
      float x1 = bb.x * SCALE_, y1 = bb.y * SCALE_;
      float x2 = (bb.x + bb.z) * SCALE_, y2 = (bb.y + bb.w) * SCALE_;
      float bw = (x2 - x1) / 3.f, bh = (y2 - y1) / 3.f;
      float area = fmaxf(bw * bh, 0.f);
      float inv = area > 0.f ? 1.f / fmaxf(area, 1e-12f) : 0.f;
      float fi = (float)i;
#pragma unroll
      for (int q = 0; q < 3; ++q) {
        float sy = y1 + q * bh;
        wyS[n*66 + q*22 + i] = hat_int(sy + bh - fi) - hat_int(sy - fi);
        float sx = x1 + q * bw;
        wxS[n*66 + q*22 + i] = (hat_int(sx + bw - fi) - hat_int(sx - fi)) * inv;
      }
    }
    __syncthreads();
    if (tid < 144) {
      int n = tid / 9, qp = tid - n*9, q = qp / 3, p = qp - q*3;
      const float* wyp = wyS + n*66 + q*22;
      const float* wxp = wxS + n*66 + p*22;
      unsigned short* out = W2d + ((size_t)b*144 + tid) * 512;
      for (int h = 0; h < 22; ++h) {
        float yv = wyp[h];
        int kb = h * 22;
#pragma unroll
        for (int w = 0; w < 22; w += 2)
          *(unsigned*)&out[kb + w] = pk_bf16(yv * wxp[w], yv * wxp[w+1]);
      }
#pragma unroll
      for (int k = 484; k < 512; k += 2) *(unsigned*)&out[k] = 0u;
    }
  } else if (bx < 2080) {              // ---- cvt_feat, 16-channel group
    int blk = bx - 32;
    const float4* src = (const float4*)(feat + (size_t)blk * 16 * 484);
    unsigned short* dstB = featB + (size_t)blk * 16 * 512;
#pragma unroll
    for (int it = 0; it < 8; ++it) {
      int j = tid + it * 256;                 // 1936 float4 total; 484/4=121 -> no row straddle
      if (j < 1936) {
        float4 v = src[j];
        int lin = j * 4;
        int c = lin / 484, w = lin - c * 484;
        uint2 pk;
        pk.x = pk_bf16(v.x, v.y); pk.y = pk_bf16(v.z, v.w);
        *(uint2*)&dstB[(size_t)c * 512 + w] = pk;
      }
    }
    if (tid < 112) {                          // zero pad k = 484..511
      int c = tid / 7, wsl = tid - c * 7;
      uint2 z; z.x = 0u; z.y = 0u;
      *(uint2*)&dstB[(size_t)c * 512 + 484 + wsl * 4] = z;
    }
  } else if (bx < 3104) {              // ---- convw_t, o = bx - 2080
    int o = bx - 2080;
    unsigned short (*T)[1028] = (unsigned short(*)[1028])psm;
    const float4* src = (const float4*)(conv_w + (size_t)o * 9216);
#pragma unroll
    for (int it = 0; it < 9; ++it) {
      int i = tid + it * 256;
      float4 v = src[i];
      int e = i * 4;
      { int c = e / 9,     qp = e - c*9;             T[qp][c] = (unsigned short)f2bf(v.x); }
      { int ee = e+1; int c = ee / 9, qp = ee - c*9; T[qp][c] = (unsigned short)f2bf(v.y); }
      { int ee = e+2; int c = ee / 9, qp = ee - c*9; T[qp][c] = (unsigned short)f2bf(v.z); }
      { int ee = e+3; int c = ee / 9, qp = ee - c*9; T[qp][c] = (unsigned short)f2bf(v.w); }
    }
    __syncthreads();
    unsigned short* dst = Wfb + (size_t)o * 9216;
#pragma unroll
    for (int qp = 0; qp < 9; ++qp) {
      uint2 w = *(const uint2*)&T[qp][tid * 4];
      ((uint2*)(dst + qp * 1024))[tid] = w;
    }
  } else {                             // ---- cvt3 (w1,w2,w3)
    int i = (bx - 3104) * 256 + tid;   // [0, 131072)
    const float* src; unsigned short* dst; int g;
    if (i < 65536)      { src = w1; dst = o1; g = i; }
    else if (i < 98304) { src = w2; dst = o2; g = i - 65536; }
    else                { src = w3; dst = o3; g = i - 98304; }
    float4 a = ((const float4*)src)[2*g];
    float4 b = ((const float4*)src)[2*g + 1];
    uint4 pk;
    pk.x = pk_bf16(a.x, a.y); pk.y = pk_bf16(a.z, a.w);
    pk.z = pk_bf16(b.x, b.y); pk.w = pk_bf16(b.z, b.w);
    ((uint4*)dst)[g] = pk;
  }
}

// ================ K2: pooling GEMM (R6-proven). Per b: X = W2d[b](144x512) . featB[b](1024x512)^T
__global__ __launch_bounds__(384) void pool_gemm(const unsigned short* __restrict__ W2d,
                                                 const unsigned short* __restrict__ featB,
                                                 unsigned short* __restrict__ X) {
  __shared__ __align__(16) unsigned short As[2][4608];
  __shared__ __align__(16) unsigned short Bs[2][4096];
  int tid = threadIdx.x;
  int nt = blockIdx.x, b = blockIdx.y;
  int lane = tid & 63, wid = tid >> 6;
  int wm = wid >> 1, wn = wid & 1;
  int l15 = lane & 15, kg = lane >> 4;
  const unsigned short* aBase = W2d  + (size_t)b * 144 * 512;
  const unsigned short* bBase = featB + ((size_t)b * 1024 + (size_t)nt * 128) * 512;
  f32x4 acc[3][4] = {};

#define ISSUEP(buf, s) do { int k0_ = (s) * 32; \
    _Pragma("unroll") for (int ii = 0; ii < 3; ++ii) { \
      int sb = ii*384 + wid*64; \
      if (sb < 1088) { \
        int slot = sb + lane; \
        if (sb < 576) { \
          int row = slot >> 2, seg = (slot & 3) ^ ((row >> 1) & 3); \
          glds16(aBase + (size_t)row*512 + k0_ + seg*8, (char*)&As[(buf)][0] + sb*16); \
        } else { \
          int s2 = slot - 576; int row = s2 >> 2, seg = (s2 & 3) ^ ((row >> 1) & 3); \
          glds16(bBase + (size_t)row*512 + k0_ + seg*8, (char*)&Bs[(buf)][0] + (sb-576)*16); \
        } } } } while (0)

  ISSUEP(0, 0);
  int cur = 0;
  for (int s = 0; s < 16; ++s) {
    __syncthreads();
    if (s < 15) ISSUEP(cur ^ 1, s + 1);
    bf16x8 af[3], bfr[4];
#pragma unroll
    for (int fm = 0; fm < 3; ++fm) {
      int r = wm*48 + fm*16 + l15;
      af[fm] = *(const bf16x8*)&As[cur][r*32 + ((kg ^ ((r >> 1) & 3)) << 3)];
    }
#pragma unroll
    for (int fn = 0; fn < 4; ++fn) {
      int r = wn*64 + fn*16 + l15;
      bfr[fn] = *(const bf16x8*)&Bs[cur][r*32 + ((kg ^ ((r >> 1) & 3)) << 3)];
    }
#pragma unroll
    for (int fm = 0; fm < 3; ++fm)
#pragma unroll
      for (int fn = 0; fn < 4; ++fn)
        acc[fm][fn] = __builtin_amdgcn_mfma_f32_16x16x32_bf16(af[fm], bfr[fn], acc[fm][fn], 0, 0, 0);
    cur ^= 1;
  }
#undef ISSUEP

#pragma unroll
  for (int fm = 0; fm < 3; ++fm)
#pragma unroll
    for (int r = 0; r < 4; ++r) {
      int m = wm*48 + fm*16 + kg*4 + r;
      int n = m / 9, qp = m - n*9;
      size_t base = ((size_t)(b*16 + n)) * KCONV + (size_t)qp * 1024 + (size_t)nt * 128;
#pragma unroll
      for (int fn = 0; fn < 4; ++fn)
        X[base + wn*64 + fn*16 + l15] = (unsigned short)f2bf(acc[fm][fn][r]);
    }
}

// ---------------- 64x64 MLP GEMM stage body (M=N=512), SK=4. blk -> (nt, mt, z).
__device__ __forceinline__ void mlp_gemm(const unsigned short* __restrict__ A,
                                         const unsigned short* __restrict__ Bm,
                                         float* __restrict__ Cp,
                                         int K, int kChunk, int blk, int tid, char* smem) {
  unsigned short* AsB = (unsigned short*)smem;           // [64][40]
  unsigned short* BsB = (unsigned short*)(smem + 5120);  // [64][40]
  int lane = tid & 63, wid = tid >> 6;
  int wm = wid >> 1, wn = wid & 1;
  int l15 = lane & 15, kg = lane >> 4;
  int nt = blk & 7, mt = (blk >> 3) & 7, z = blk >> 6;
  int kbeg = z * kChunk, kend = kbeg + kChunk;
  int srow = tid >> 2, sseg = tid & 3;
  const unsigned short* aG = A  + (size_t)(mt*64 + srow) * K + sseg * 8;
  const unsigned short* bG = Bm + (size_t)(nt*64 + srow) * K + sseg * 8;
  f32x4 acc[2][2] = {};

  for (int k0 = kbeg; k0 < kend; k0 += 32) {
    uint4 av = *(const uint4*)(aG + k0);
    uint4 bv = *(const uint4*)(bG + k0);
    __syncthreads();
    *(uint4*)&AsB[srow*40 + sseg*8] = av;
    *(uint4*)&BsB[srow*40 + sseg*8] = bv;
    __syncthreads();
    bf16x8 a0 = *(const bf16x8*)&AsB[(wm*32 +      l15)*40 + kg*8];
    bf16x8 a1 = *(const bf16x8*)&AsB[(wm*32 + 16 + l15)*40 + kg*8];
    bf16x8 b0 = *(const bf16x8*)&BsB[(wn*32 +      l15)*40 + kg*8];
    bf16x8 b1 = *(const bf16x8*)&BsB[(wn*32 + 16 + l15)*40 + kg*8];
    acc[0][0] = __builtin_amdgcn_mfma_f32_16x16x32_bf16(a0, b0, acc[0][0], 0, 0, 0);
    acc[0][1] = __builtin_amdgcn_mfma_f32_16x16x32_bf16(a0, b1, acc[0][1], 0, 0, 0);
    acc[1][0] = __builtin_amdgcn_mfma_f32_16x16x32_bf16(a1, b0, acc[1][0], 0, 0, 0);
    acc[1][1] = __builtin_amdgcn_mfma_f32_16x16x32_bf16(a1, b1, acc[1][1], 0, 0, 0);
  }

  float* cp = Cp + ((size_t)z * 512 + (size_t)mt * 64) * 512 + (size_t)nt * 64;
#pragma unroll
  for (int fm = 0; fm < 2; ++fm)
#pragma unroll
    for (int fn = 0; fn < 2; ++fn)
#pragma unroll
      for (int r = 0; r < 4; ++r) {
        int row = wm*32 + fm*16 + kg*4 + r;
        int col = wn*32 + fn*16 + l15;
        cp[(size_t)row * 512 + col] = acc[fm][fn][r];
      }
}

// ---------------- parallel SK=4 reduce + epilogue (i = group of 4 floats, N=512)
__device__ __forceinline__ void red4(const float* __restrict__ Cp, int i,
                                     const float* __restrict__ bias,
                                     unsigned short* __restrict__ outb,
                                     float* __restrict__ outf) {
  float4 s = ((const float4*)Cp)[i];
#pragma unroll
  for (int z2 = 1; z2 < 4; ++z2) {
    float4 t = ((const float4*)Cp)[(size_t)z2 * 65536 + i];
    s.x += t.x; s.y += t.y; s.z += t.z; s.w += t.w;
  }
  int n0 = (i * 4) & 511;
  if (outb) {
    uint2 pk;
    pk.x = pk_bf16(fmaxf(s.x + bias[n0], 0.f),   fmaxf(s.y + bias[n0+1], 0.f));
    pk.y = pk_bf16(fmaxf(s.z + bias[n0+2], 0.f), fmaxf(s.w + bias[n0+3], 0.f));
    *(uint2*)&outb[(size_t)i * 4] = pk;
  } else {
    float4 o;
    o.x = s.x + bias[n0];   o.y = s.y + bias[n0+1];
    o.z = s.z + bias[n0+2]; o.w = s.w + bias[n0+3];
    ((float4*)outf)[i] = o;
  }
}

// ================ K3: cooperative conv GEMM + full tail. 256 blocks x 256 thr.
__global__ __launch_bounds__(256) void conv_tail(
    const unsigned short* __restrict__ Xb, const unsigned short* __restrict__ Wfb,
    const unsigned short* __restrict__ w1b, const unsigned short* __restrict__ w2b,
    const unsigned short* __restrict__ w3b,
    float* __restrict__ part,
    unsigned short* __restrict__ H0, unsigned short* __restrict__ H1,
    unsigned short* __restrict__ H2,
    const float* __restrict__ conv_b, const float* __restrict__ gamma,
    const float* __restrict__ beta, const float* __restrict__ mu,
    const float* __restrict__ var,
    const float* __restrict__ b1, const float* __restrict__ b2,
    const float* __restrict__ b3, float* __restrict__ outF)
{
  __shared__ __align__(16) char smem[32768];
  cg::grid_group grid = cg::this_grid();
  int tid = threadIdx.x, blk = blockIdx.x;
  int lane = tid & 63, wid = tid >> 6;
  int wm = wid >> 1, wn = wid & 1;
  int l15 = lane & 15, kg = lane >> 4;

  // ---- Stage 1: conv GEMM [512,9216]x[1024,9216]^T, 128^2, SK=8 (verbatim gemm128 body)
  {
    const int K = KCONV, N = 1024, M = 512;
    int nt = blk & 7, mt = (blk >> 3) & 3, z = blk >> 5;
    int kbeg = z * 1152;
    int row0 = tid >> 2, row1 = 64 + row0;
    int slot = tid & 3;
    int s0 = slot ^ ((row0 >> 1) & 3);
    int s1 = slot ^ ((row1 >> 1) & 3);
    const unsigned short* ga0 = Xb  + (size_t)(mt*128 + row0) * K + kbeg + s0*8;
    const unsigned short* ga1 = Xb  + (size_t)(mt*128 + row1) * K + kbeg + s1*8;
    const unsigned short* gb0 = Wfb + (size_t)(nt*128 + row0) * K + kbeg + s0*8;
    const unsigned short* gb1 = Wfb + (size_t)(nt*128 + row1) * K + kbeg + s1*8;
    int wbyte = wid * 1024;
    unsigned short* AsB = (unsigned short*)smem;            // 2 bufs x 4096 u16
    unsigned short* BsB = (unsigned short*)(smem + 16384);
    f32x4 acc[4][4] = {};
    int cur = 0;

#define ISSUE(buf, s) do { int ko = (s) * 32; \
    glds16(ga0 + ko, (char*)AsB + (buf)*8192 + wbyte); \
    glds16(ga1 + ko, (char*)AsB + (buf)*8192 + 4096 + wbyte); \
    glds16(gb0 + ko, (char*)BsB + (buf)*8192 + wbyte); \
    glds16(gb1 + ko, (char*)BsB + (buf)*8192 + 4096 + wbyte); } while (0)

    ISSUE(0, 0);
    for (int s = 0; s < 36; ++s) {
      __syncthreads();
      if (s + 1 < 36) ISSUE(cur ^ 1, s + 1);
      bf16x8 af[4], bfr[4];
#pragma unroll
      for (int fm = 0; fm < 4; ++fm) {
        int fr = wm*64 + fm*16 + l15;
        af[fm] = *(const bf16x8*)&AsB[cur*4096 + fr*32 + ((kg ^ ((fr >> 1) & 3)) << 3)];
      }
#pragma unroll
      for (int fn = 0; fn < 4; ++fn) {
        int fr = wn*64 + fn*16 + l15;
        bfr[fn] = *(const bf16x8*)&BsB[cur*4096 + fr*32 + ((kg ^ ((fr >> 1) & 3)) << 3)];
      }
#pragma unroll
      for (int fm = 0; fm < 4; ++fm)
#pragma unroll
        for (int fn = 0; fn < 4; ++fn)
          acc[fm][fn] = __builtin_amdgcn_mfma_f32_16x16x32_bf16(af[fm], bfr[fn], acc[fm][fn], 0, 0, 0);
      cur ^= 1;
    }
#undef ISSUE

    float* cp = part + ((size_t)z * M + (size_t)mt * 128) * N + (size_t)nt * 128;
#pragma unroll
    for (int fm = 0; fm < 4; ++fm)
#pragma unroll
      for (int fn = 0; fn < 4; ++fn)
#pragma unroll
        for (int r = 0; r < 4; ++r) {
          int row = wm*64 + fm*16 + kg*4 + r;
          int col = wn*64 + fn*16 + l15;
          cp[(size_t)row * N + col] = acc[fm][fn][r];
        }
  }
  __threadfence(); grid.sync();

  // ---- Stage 2: parallel SK=8 reduce + BN + ReLU -> H0 (bf16)
  {
#pragma unroll
    for (int rep = 0; rep < 2; ++rep) {
      int i = blk * 256 + tid + rep * 65536;       // [0, 131072)
      float4 s = ((const float4*)part)[i];
#pragma unroll
      for (int z2 = 1; z2 < 8; ++z2) {
        float4 t = ((const float4*)part)[(size_t)z2 * 131072 + i];
        s.x += t.x; s.y += t.y; s.z += t.z; s.w += t.w;
      }
      int n0 = (i * 4) & 1023;
      float o[4] = {s.x, s.y, s.z, s.w};
#pragma unroll
      for (int j = 0; j < 4; ++j) {
        int n = n0 + j;
        float sc = gamma[n] * rsqrtf(var[n] + EPS_);
        o[j] = fmaxf((o[j] + conv_b[n] - mu[n]) * sc + beta[n], 0.f);
      }
      uint2 pk; pk.x = pk_bf16(o[0], o[1]); pk.y = pk_bf16(o[2], o[3]);
      *(uint2*)&H0[(size_t)i * 4] = pk;
    }
  }
  __threadfence(); grid.sync();

  // ---- Stage 3/4: MLP1 (K=1024, SK=4) + reduce
  mlp_gemm(H0, w1b, part, 1024, 256, blk, tid, smem);
  __threadfence(); grid.sync();
  red4(part, blk * 256 + tid, b1, H1, nullptr);
  __threadfence(); grid.sync();

  // ---- Stage 5/6: MLP2 (K=512, SK=4) + reduce
  mlp_gemm(H1, w2b, part, 512, 128, blk, tid, smem);
  __threadfence(); grid.sync();
  red4(part, blk * 256 + tid, b2, H2, nullptr);
  __threadfence(); grid.sync();

  // ---- Stage 7/8: MLP3 (K=512, SK=4) + bias -> fp32 out
  mlp_gemm(H2, w3b, part, 512, 128, blk, tid, smem);
  __threadfence(); grid.sync();
  red4(part, blk * 256 + tid, b3, nullptr, outF);
}

extern "C" void kernel_launch(void* const* d_in, const int* in_sizes, int n_in,
                              void* d_out, int out_size, void* d_ws, size_t ws_size,
                              hipStream_t stream) {
  const float* feat   = (const float*)d_in[0];
  const float* bbox   = (const float*)d_in[1];
  const float* conv_w = (const float*)d_in[2];
  const float* conv_b = (const float*)d_in[3];
  const float* gamma  = (const float*)d_in[4];
  const float* beta   = (const float*)d_in[5];
  const float* mean   = (const float*)d_in[6];
  const float* var    = (const float*)d_in[7];
  const float* w1     = (const float*)d_in[8];
  const float* b1     = (const float*)d_in[9];
  const float* w2     = (const float*)d_in[10];
  const float* b2     = (const float*)d_in[11];
  const float* w3     = (const float*)d_in[12];
  const float* b3     = (const float*)d_in[13];

  char* ws = (char*)d_ws;
  // region A [0, 38273024): W2d + featB — dead after pool_gemm; part/H* overlay it.
  unsigned short* W2d  = (unsigned short*)(ws);              //  4718592 B [32][144][512]
  unsigned short* featB= (unsigned short*)(ws + 4718592);    // 33554432 B [32][1024][512]
  float*          part = (float*)(ws);                       // 16777216 B (overlay)
  unsigned short* H0   = (unsigned short*)(ws + 16777216);   //  1048576 B (overlay)
  unsigned short* H1   = (unsigned short*)(ws + 17825792);   //   524288 B (overlay)
  unsigned short* H2   = (unsigned short*)(ws + 18350080);   //   524288 B (overlay)
  unsigned short* Xb   = (unsigned short*)(ws + 38273024);   //  9437184 B [512][9216]
  unsigned short* Wfb  = (unsigned short*)(ws + 47710208);   // 18874368 B [1024][9216]
  unsigned short* w1b  = (unsigned short*)(ws + 66584576);   //  1048576 B
  unsigned short* w2b  = (unsigned short*)(ws + 67633152);   //   524288 B
  unsigned short* w3b  = (unsigned short*)(ws + 68157440);   //   524288 B  (total 68681728 B)

  prep_all<<<3616, 256, 0, stream>>>(bbox, feat, conv_w, w1, w2, w3,
                                     W2d, featB, Wfb, w1b, w2b, w3b);

  pool_gemm<<<dim3(8, 32), 384, 0, stream>>>(W2d, featB, Xb);

  float* outF = (float*)d_out;
  void* args[] = {(void*)&Xb, (void*)&Wfb, (void*)&w1b, (void*)&w2b, (void*)&w3b,
                  (void*)&part, (void*)&H0, (void*)&H1, (void*)&H2,
                  (void*)&conv_b, (void*)&gamma, (void*)&beta, (void*)&mean, (void*)&var,
                  (void*)&b1, (void*)&b2, (void*)&b3, (void*)&outF};
  hipLaunchCooperativeKernel((const void*)conv_tail, dim3(256), dim3(256), args, 0, stream);
}

// Round 8
// 129.419 us; speedup vs baseline: 3.8097x; 3.8097x over previous
//
#include <hip/hip_runtime.h>
#include <hip/hip_bf16.h>

#define B_    32
#define NBB_  16
#define C_    1024
#define NROI  512
#define KCONV 9216
#define SCALE_ (1.0f/16.0f)
#define EPS_  1e-5f

using f32x4  = __attribute__((ext_vector_type(4))) float;
using bf16x8 = __attribute__((ext_vector_type(8))) short;

__device__ __forceinline__ unsigned f2bf(float f) {
  union { float f; unsigned u; } x; x.f = f;
  unsigned r = x.u + 0x7fffu + ((x.u >> 16) & 1u);   // RNE
  return r >> 16;
}

__device__ __forceinline__ unsigned pk_bf16(float lo, float hi) {
  __hip_bfloat162 h = __float22bfloat162_rn(make_float2(lo, hi));
  return *reinterpret_cast<unsigned*>(&h);
}

__device__ __forceinline__ float hat_int(float t) {
  t = fminf(fmaxf(t, -1.f), 1.f);
  return t + 0.5f - 0.5f * t * fabsf(t);
}

__device__ __forceinline__ void glds16(const void* g, void* l) {
  __builtin_amdgcn_global_load_lds((const __attribute__((address_space(1))) void*)g,
                                   (__attribute__((address_space(3))) void*)l, 16, 0, 0);
}

// ---------------- K0a: per-ROI separable integral weights (R2-proven)
__global__ __launch_bounds__(32) void prep_rois(const float* __restrict__ bbox,
                                                float* __restrict__ wy,
                                                float* __restrict__ wx) {
  int r = blockIdx.x;
  float4 bb = ((const float4*)bbox)[r];
  float x1 = bb.x * SCALE_, y1 = bb.y * SCALE_;
  float x2 = (bb.x + bb.z) * SCALE_, y2 = (bb.y + bb.w) * SCALE_;
  float bw = (x2 - x1) / 3.f, bh = (y2 - y1) / 3.f;
  float area = fmaxf(bw * bh, 0.f);
  float inv = area > 0.f ? 1.f / fmaxf(area, 1e-12f) : 0.f;
  int i = threadIdx.x;
  if (i < 22) {
    float fi = (float)i;
#pragma unroll
    for (int q = 0; q < 3; ++q) {
      float sy = y1 + q * bh;
      wy[r*66 + q*22 + i] = hat_int(sy + bh - fi) - hat_int(sy - fi);
      float sx = x1 + q * bw;
      wx[r*66 + q*22 + i] = (hat_int(sx + bw - fi) - hat_int(sx - fi)) * inv;
    }
  }
}

// ---------------- K0b: W2d[b][(n,qp)][k=h*22+w] = wy*wx, bf16, K pad 512 (R2-proven)
__global__ __launch_bounds__(192) void w2d_build(const float* __restrict__ wy,
                                                 const float* __restrict__ wx,
                                                 unsigned short* __restrict__ W2d) {
  __shared__ float wyS[1056], wxS[1056];
  int b = blockIdx.x, tid = threadIdx.x;
  for (int i = tid; i < 1056; i += 192) { wyS[i] = wy[(size_t)b*1056 + i]; wxS[i] = wx[(size_t)b*1056 + i]; }
  __syncthreads();
  if (tid < 144) {
    int n = tid / 9, qp = tid - n*9, q = qp / 3, p = qp - q*3;
    const float* wyp = wyS + n*66 + q*22;
    const float* wxp = wxS + n*66 + p*22;
    unsigned short* out = W2d + ((size_t)b*144 + tid) * 512;
    for (int h = 0; h < 22; ++h) {
      float yv = wyp[h];
      int kb = h * 22;
#pragma unroll
      for (int w = 0; w < 22; w += 2)
        *(unsigned*)&out[kb + w] = pk_bf16(yv * wxp[w], yv * wxp[w+1]);
    }
    for (int k = 484; k < 512; k += 2) *(unsigned*)&out[k] = 0u;
  }
}

// ---------------- K1: fused fp32->bf16 for w1,w2,w3 (R5-proven)
__global__ __launch_bounds__(256) void cvt3_bf16(const float* __restrict__ w1, const float* __restrict__ w2,
                                                 const float* __restrict__ w3,
                                                 unsigned short* __restrict__ o1, unsigned short* __restrict__ o2,
                                                 unsigned short* __restrict__ o3) {
  int i = blockIdx.x * 256 + threadIdx.x;
  const float* src; unsigned short* dst; int g;
  if (i < 65536)      { src = w1; dst = o1; g = i; }
  else if (i < 98304) { src = w2; dst = o2; g = i - 65536; }
  else                { src = w3; dst = o3; g = i - 98304; }
  float4 a = ((const float4*)src)[2*g];
  float4 b = ((const float4*)src)[2*g + 1];
  uint4 pk;
  pk.x = pk_bf16(a.x, a.y); pk.y = pk_bf16(a.z, a.w);
  pk.z = pk_bf16(b.x, b.y); pk.w = pk_bf16(b.z, b.w);
  ((uint4*)dst)[g] = pk;
}

// ---------------- K1b: conv_w [o][c][qp] fp32 -> Wfb[o][qp*1024 + c] bf16 (R3-proven, 4096 blocks)
__global__ __launch_bounds__(256) void convw_t(const float* __restrict__ cw,
                                               unsigned short* __restrict__ out) {
  __shared__ float T[9][260];
  int o = blockIdx.x, cc = blockIdx.y;   // cc: 256-channel chunk 0..3
  int tid = threadIdx.x;
  const float* src = cw + (size_t)o * 9216 + (size_t)cc * 2304;
  for (int i = tid; i < 576; i += 256) {
    float4 v = ((const float4*)src)[i];
    int e = i * 4;
#pragma unroll
    for (int j = 0; j < 4; ++j) {
      int ee = e + j;
      int c = ee / 9, qp = ee - c * 9;
      T[qp][c] = ((const float*)&v)[j];
    }
  }
  __syncthreads();
  unsigned short* dst = out + (size_t)o * 9216 + cc * 256 + tid;
#pragma unroll
  for (int qp = 0; qp < 9; ++qp) dst[qp * 1024] = (unsigned short)f2bf(T[qp][tid]);
}

// ---------------- K2: pooling GEMM (R4-proven, <38 µs). X[(b,n)][qp*1024+c] = W2d[b] . feat[b]^T
// Block (nch, b); 384 thr = 6 waves (3wm x 2wn). M=144, N=64, K=512(484).
// A-fragments direct from global (L2-resident); B staged reg->LDS with T14 prefetch.
__global__ __launch_bounds__(384) void pool_gemm(const float* __restrict__ feat,
                                                 const unsigned short* __restrict__ W2d,
                                                 unsigned short* __restrict__ X) {
  __shared__ __align__(16) unsigned short Bs[64 * 72];   // 9216 B
  int tid = threadIdx.x;
  int nch = blockIdx.x, b = blockIdx.y;
  int lane = tid & 63, wid = tid >> 6;
  int wm = wid >> 1, wn = wid & 1;
  int l15 = lane & 15, kg = lane >> 4;
  const unsigned short* w2b = W2d + (size_t)b * 144 * 512;
  const float* fb = feat + ((size_t)b * C_ + (size_t)nch * 64) * 484;
  f32x4 acc[3][2] = {};

  int c0 = tid >> 4,        f40 = tid & 15;
  int i1 = tid + 384;  int c1 = i1 >> 4, f41 = i1 & 15;
  int i2 = tid + 768;  bool has2 = i2 < 1024; int c2 = i2 >> 4, f42 = i2 & 15;
  float4 bR0, bR1, bR2;

#define LOADB(s) do { \
    bR0 = (((s) < 7 || f40 <= 8) ? *(const float4*)(fb + (size_t)c0*484 + (s)*64 + f40*4) : make_float4(0,0,0,0)); \
    bR1 = (((s) < 7 || f41 <= 8) ? *(const float4*)(fb + (size_t)c1*484 + (s)*64 + f41*4) : make_float4(0,0,0,0)); \
    if (has2) bR2 = (((s) < 7 || f42 <= 8) ? *(const float4*)(fb + (size_t)c2*484 + (s)*64 + f42*4) : make_float4(0,0,0,0)); \
  } while (0)

  LOADB(0);
#pragma unroll
  for (int s = 0; s < 8; ++s) {
    __syncthreads();                       // prev step's Bs reads complete
    {
      uint2 p0; p0.x = pk_bf16(bR0.x, bR0.y); p0.y = pk_bf16(bR0.z, bR0.w);
      *(uint2*)&Bs[c0*72 + f40*4] = p0;
      uint2 p1; p1.x = pk_bf16(bR1.x, bR1.y); p1.y = pk_bf16(bR1.z, bR1.w);
      *(uint2*)&Bs[c1*72 + f41*4] = p1;
      if (has2) {
        uint2 p2; p2.x = pk_bf16(bR2.x, bR2.y); p2.y = pk_bf16(bR2.z, bR2.w);
        *(uint2*)&Bs[c2*72 + f42*4] = p2;
      }
    }
    if (s < 7) LOADB(s + 1);               // T14: issue next-step loads before compute
    __syncthreads();                       // Bs ready

    bf16x8 af[3][2], bf[2][2];
#pragma unroll
    for (int fm = 0; fm < 3; ++fm)
#pragma unroll
      for (int kk = 0; kk < 2; ++kk)
        af[fm][kk] = *(const bf16x8*)(w2b + (size_t)(wm*48 + fm*16 + l15) * 512 + s*64 + kk*32 + kg*8);
#pragma unroll
    for (int fn = 0; fn < 2; ++fn)
#pragma unroll
      for (int kk = 0; kk < 2; ++kk)
        bf[fn][kk] = *(const bf16x8*)&Bs[(wn*32 + fn*16 + l15) * 72 + kk*32 + kg*8];
#pragma unroll
    for (int fm = 0; fm < 3; ++fm)
#pragma unroll
      for (int fn = 0; fn < 2; ++fn) {
        acc[fm][fn] = __builtin_amdgcn_mfma_f32_16x16x32_bf16(af[fm][0], bf[fn][0], acc[fm][fn], 0, 0, 0);
        acc[fm][fn] = __builtin_amdgcn_mfma_f32_16x16x32_bf16(af[fm][1], bf[fn][1], acc[fm][fn], 0, 0, 0);
      }
  }
#undef LOADB

#pragma unroll
  for (int fm = 0; fm < 3; ++fm)
#pragma unroll
    for (int r = 0; r < 4; ++r) {
      int m = wm*48 + fm*16 + kg*4 + r;
      int n = m / 9, qp = m - n*9;
      size_t base = ((size_t)(b*16 + n)) * KCONV + (size_t)qp * 1024 + (size_t)nch * 64;
#pragma unroll
      for (int fn = 0; fn < 2; ++fn)
        X[base + wn*32 + fn*16 + l15] = (unsigned short)f2bf(acc[fm][fn][r]);
    }
}

// ---------------- K3: 128x128 NT GEMM, glds16 + dbuf + XOR swizzle, split-K partials (proven)
__global__ __launch_bounds__(256) void gemm128(const unsigned short* __restrict__ A,
                                               const unsigned short* __restrict__ Bm,
                                               float* __restrict__ Cp,
                                               int M, int N, int K, int kChunk) {
  __shared__ __align__(16) unsigned short As[2][4096];
  __shared__ __align__(16) unsigned short Bs[2][4096];
  int tid = threadIdx.x;
  int lane = tid & 63, wid = tid >> 6;
  int wm = wid >> 1, wn = wid & 1;
  int l15 = lane & 15, kg = lane >> 4;
  int nt = blockIdx.x, mt = blockIdx.y, z = blockIdx.z;
  int kbeg = z * kChunk;
  int steps = kChunk / 32;

  int row0 = tid >> 2, row1 = 64 + row0;
  int slot = tid & 3;
  int s0 = slot ^ ((row0 >> 1) & 3);
  int s1 = slot ^ ((row1 >> 1) & 3);
  const unsigned short* ga0 = A  + (size_t)(mt*128 + row0) * K + kbeg + s0*8;
  const unsigned short* ga1 = A  + (size_t)(mt*128 + row1) * K + kbeg + s1*8;
  const unsigned short* gb0 = Bm + (size_t)(nt*128 + row0) * K + kbeg + s0*8;
  const unsigned short* gb1 = Bm + (size_t)(nt*128 + row1) * K + kbeg + s1*8;
  int wbyte = wid * 1024;

  f32x4 acc[4][4] = {};
  int cur = 0;

#define ISSUE(buf, s) do { int ko = (s) * 32; \
    glds16(ga0 + ko, (char*)&As[(buf)][0] + wbyte); \
    glds16(ga1 + ko, (char*)&As[(buf)][0] + 4096 + wbyte); \
    glds16(gb0 + ko, (char*)&Bs[(buf)][0] + wbyte); \
    glds16(gb1 + ko, (char*)&Bs[(buf)][0] + 4096 + wbyte); } while (0)

  ISSUE(0, 0);
  for (int s = 0; s < steps; ++s) {
    __syncthreads();
    if (s + 1 < steps) ISSUE(cur ^ 1, s + 1);
    bf16x8 af[4], bfr[4];
#pragma unroll
    for (int fm = 0; fm < 4; ++fm) {
      int fr = wm*64 + fm*16 + l15;
      af[fm] = *(const bf16x8*)&As[cur][fr*32 + ((kg ^ ((fr >> 1) & 3)) << 3)];
    }
#pragma unroll
    for (int fn = 0; fn < 4; ++fn) {
      int fr = wn*64 + fn*16 + l15;
      bfr[fn] = *(const bf16x8*)&Bs[cur][fr*32 + ((kg ^ ((fr >> 1) & 3)) << 3)];
    }
#pragma unroll
    for (int fm = 0; fm < 4; ++fm)
#pragma unroll
      for (int fn = 0; fn < 4; ++fn)
        acc[fm][fn] = __builtin_amdgcn_mfma_f32_16x16x32_bf16(af[fm], bfr[fn], acc[fm][fn], 0, 0, 0);
    cur ^= 1;
  }
#undef ISSUE

  float* cp = Cp + ((size_t)z * M + (size_t)mt * 128) * N + (size_t)nt * 128;
#pragma unroll
  for (int fm = 0; fm < 4; ++fm)
#pragma unroll
    for (int fn = 0; fn < 4; ++fn)
#pragma unroll
      for (int r = 0; r < 4; ++r) {
        int row = wm*64 + fm*16 + kg*4 + r;
        int col = wn*64 + fn*16 + l15;
        cp[(size_t)row * N + col] = acc[fm][fn][r];
      }
}

// ---------------- K3b: 64x64 NT GEMM (MLP sizes), split-K partials (proven)
__global__ __launch_bounds__(256) void gemm_nt(const unsigned short* __restrict__ A,
                                               const unsigned short* __restrict__ Bm,
                                               float* __restrict__ Cp,
                                               int M, int N, int K, int kChunk) {
  __shared__ __align__(16) unsigned short As[64][40];
  __shared__ __align__(16) unsigned short Bs[64][40];
  int tid = threadIdx.x;
  int lane = tid & 63, wid = tid >> 6;
  int wm = wid >> 1, wn = wid & 1;
  int l15 = lane & 15, kg = lane >> 4;
  int nt = blockIdx.x, mt = blockIdx.y, z = blockIdx.z;
  int kbeg = z * kChunk;
  int kend = kbeg + kChunk; if (kend > K) kend = K;
  int srow = tid >> 2, sseg = tid & 3;
  const unsigned short* aG = A  + (size_t)(mt*64 + srow) * K + sseg * 8;
  const unsigned short* bG = Bm + (size_t)(nt*64 + srow) * K + sseg * 8;
  f32x4 acc[2][2] = {};

  for (int k0 = kbeg; k0 < kend; k0 += 32) {
    uint4 av = *(const uint4*)(aG + k0);
    uint4 bv = *(const uint4*)(bG + k0);
    __syncthreads();
    *(uint4*)&As[srow][sseg*8] = av;
    *(uint4*)&Bs[srow][sseg*8] = bv;
    __syncthreads();
    bf16x8 a0 = *(const bf16x8*)&As[wm*32 +      l15][kg*8];
    bf16x8 a1 = *(const bf16x8*)&As[wm*32 + 16 + l15][kg*8];
    bf16x8 b0 = *(const bf16x8*)&Bs[wn*32 +      l15][kg*8];
    bf16x8 b1 = *(const bf16x8*)&Bs[wn*32 + 16 + l15][kg*8];
    acc[0][0] = __builtin_amdgcn_mfma_f32_16x16x32_bf16(a0, b0, acc[0][0], 0, 0, 0);
    acc[0][1] = __builtin_amdgcn_mfma_f32_16x16x32_bf16(a0, b1, acc[0][1], 0, 0, 0);
    acc[1][0] = __builtin_amdgcn_mfma_f32_16x16x32_bf16(a1, b0, acc[1][0], 0, 0, 0);
    acc[1][1] = __builtin_amdgcn_mfma_f32_16x16x32_bf16(a1, b1, acc[1][1], 0, 0, 0);
  }

  float* cp = Cp + ((size_t)z * M + (size_t)mt * 64) * N + (size_t)nt * 64;
#pragma unroll
  for (int fm = 0; fm < 2; ++fm)
#pragma unroll
    for (int fn = 0; fn < 2; ++fn)
#pragma unroll
      for (int r = 0; r < 4; ++r) {
        int row = wm*32 + fm*16 + kg*4 + r;
        int col = wn*32 + fn*16 + l15;
        cp[(size_t)row * N + col] = acc[fm][fn][r];
      }
}

// ---------------- K4: parallel split-K reduce + epilogue (R4-proven)
template<int MODE>
__global__ __launch_bounds__(256) void epi(const float* __restrict__ Cp, int SK, int MN4, int N,
                                           const float* __restrict__ bias,
                                           const float* __restrict__ g,
                                           const float* __restrict__ be,
                                           const float* __restrict__ mu,
                                           const float* __restrict__ var,
                                           unsigned short* __restrict__ outb,
                                           float* __restrict__ outf) {
  int i = blockIdx.x * 256 + threadIdx.x;
  if (i >= MN4) return;
  float4 s = ((const float4*)Cp)[i];
  for (int z = 1; z < SK; ++z) {
    float4 t = ((const float4*)Cp)[(size_t)z * MN4 + i];
    s.x += t.x; s.y += t.y; s.z += t.z; s.w += t.w;
  }
  int n0 = (i * 4) % N;
  float v[4] = {s.x, s.y, s.z, s.w};
  if (MODE == 0) {
    float o[4];
#pragma unroll
    for (int j = 0; j < 4; ++j) {
      int n = n0 + j;
      float sc = g[n] * rsqrtf(var[n] + EPS_);
      o[j] = fmaxf((v[j] + bias[n] - mu[n]) * sc + be[n], 0.f);
    }
    uint2 pk; pk.x = pk_bf16(o[0], o[1]); pk.y = pk_bf16(o[2], o[3]);
    *(uint2*)&outb[(size_t)i * 4] = pk;
  } else if (MODE == 1) {
    uint2 pk;
    pk.x = pk_bf16(fmaxf(v[0] + bias[n0], 0.f),   fmaxf(v[1] + bias[n0+1], 0.f));
    pk.y = pk_bf16(fmaxf(v[2] + bias[n0+2], 0.f), fmaxf(v[3] + bias[n0+3], 0.f));
    *(uint2*)&outb[(size_t)i * 4] = pk;
  } else {
    float4 o;
    o.x = v[0] + bias[n0];     o.y = v[1] + bias[n0 + 1];
    o.z = v[2] + bias[n0 + 2]; o.w = v[3] + bias[n0 + 3];
    ((float4*)outf)[i] = o;
  }
}

extern "C" void kernel_launch(void* const* d_in, const int* in_sizes, int n_in,
                              void* d_out, int out_size, void* d_ws, size_t ws_size,
                              hipStream_t stream) {
  const float* feat   = (const float*)d_in[0];
  const float* bbox   = (const float*)d_in[1];
  const float* conv_w = (const float*)d_in[2];
  const float* conv_b = (const float*)d_in[3];
  const float* gamma  = (const float*)d_in[4];
  const float* beta   = (const float*)d_in[5];
  const float* mean   = (const float*)d_in[6];
  const float* var    = (const float*)d_in[7];
  const float* w1     = (const float*)d_in[8];
  const float* b1     = (const float*)d_in[9];
  const float* w2     = (const float*)d_in[10];
  const float* b2     = (const float*)d_in[11];
  const float* w3     = (const float*)d_in[12];
  const float* b3     = (const float*)d_in[13];

  char* ws = (char*)d_ws;
  float*          wy  = (float*)(ws);                       //   135168 B
  float*          wx  = (float*)(ws + 135168);              //   135168 B
  unsigned short* W2d = (unsigned short*)(ws + 270336);     //  4718592 B [32][144][512]
  unsigned short* Xb  = (unsigned short*)(ws + 4988928);    //  9437184 B [512][9216]
  unsigned short* Wfb = (unsigned short*)(ws + 14426112);   // 18874368 B [1024][9216] (qp-major)
  unsigned short* w1b = (unsigned short*)(ws + 33300480);   //  1048576 B
  unsigned short* w2b = (unsigned short*)(ws + 34349056);   //   524288 B
  unsigned short* w3b = (unsigned short*)(ws + 34873344);   //   524288 B
  float*          part= (float*)(ws + 35397632);            // 16777216 B [8][512][1024] f32
  unsigned short* H0  = (unsigned short*)(ws + 52174848);   //  1048576 B
  unsigned short* H1  = (unsigned short*)(ws + 53223424);   //   524288 B
  unsigned short* H2  = (unsigned short*)(ws + 53747712);   //   524288 B (total 54272000 B)

  prep_rois<<<NROI, 32, 0, stream>>>(bbox, wy, wx);
  w2d_build<<<32, 192, 0, stream>>>(wy, wx, W2d);
  convw_t<<<dim3(1024, 4), 256, 0, stream>>>(conv_w, Wfb);
  cvt3_bf16<<<512, 256, 0, stream>>>(w1, w2, w3, w1b, w2b, w3b);

  // pooling GEMM: per-b, M=144, N=1024 (16 chunks of 64), K=512
  pool_gemm<<<dim3(16, 32), 384, 0, stream>>>(feat, W2d, Xb);

  // conv GEMM: [512,9216] x [1024,9216]^T, 128^2 tiles, SK=8 -> 256 blocks
  gemm128<<<dim3(8, 4, 8), 256, 0, stream>>>(Xb, Wfb, part, 512, 1024, 9216, 1152);
  epi<0><<<(131072 + 255) / 256, 256, 0, stream>>>(part, 8, 131072, 1024,
      conv_b, gamma, beta, mean, var, H0, nullptr);

  // MLP1: [512,1024] x [512,1024]^T, SK=4
  gemm_nt<<<dim3(8, 8, 4), 256, 0, stream>>>(H0, w1b, part, 512, 512, 1024, 256);
  epi<1><<<(65536 + 255) / 256, 256, 0, stream>>>(part, 4, 65536, 512,
      b1, nullptr, nullptr, nullptr, nullptr, H1, nullptr);

  // MLP2: [512,512] x [512,512]^T, SK=4
  gemm_nt<<<dim3(8, 8, 4), 256, 0, stream>>>(H1, w2b, part, 512, 512, 512, 128);
  epi<1><<<(65536 + 255) / 256, 256, 0, stream>>>(part, 4, 65536, 512,
      b2, nullptr, nullptr, nullptr, nullptr, H2, nullptr);

  // MLP3: [512,512] x [512,512]^T, SK=4, fp32 out
  gemm_nt<<<dim3(8, 8, 4), 256, 0, stream>>>(H2, w3b, part, 512, 512, 512, 128);
  epi<2><<<(65536 + 255) / 256, 256, 0, stream>>>(part, 4, 65536, 512,
      b3, nullptr, nullptr, nullptr, nullptr, nullptr, (float*)d_out);
}

// Round 9
// 124.433 us; speedup vs baseline: 3.9623x; 1.0401x over previous
//
#include <hip/hip_runtime.h>
#include <hip/hip_bf16.h>

#define B_    32
#define NBB_  16
#define C_    1024
#define NROI  512
#define KCONV 9216
#define SCALE_ (1.0f/16.0f)
#define EPS_  1e-5f

using f32x4  = __attribute__((ext_vector_type(4))) float;
using bf16x8 = __attribute__((ext_vector_type(8))) short;

__device__ __forceinline__ unsigned f2bf(float f) {
  union { float f; unsigned u; } x; x.f = f;
  unsigned r = x.u + 0x7fffu + ((x.u >> 16) & 1u);   // RNE
  return r >> 16;
}

__device__ __forceinline__ unsigned pk_bf16(float lo, float hi) {
  __hip_bfloat162 h = __float22bfloat162_rn(make_float2(lo, hi));
  return *reinterpret_cast<unsigned*>(&h);
}

__device__ __forceinline__ float hat_int(float t) {
  t = fminf(fmaxf(t, -1.f), 1.f);
  return t + 0.5f - 0.5f * t * fabsf(t);
}

__device__ __forceinline__ void glds16(const void* g, void* l) {
  __builtin_amdgcn_global_load_lds((const __attribute__((address_space(1))) void*)g,
                                   (__attribute__((address_space(3))) void*)l, 16, 0, 0);
}

// ================ K1: ALL preprocessing in one launch (R7-proven branches, cvt_feat removed).
// blocks [0,32): ROI weights -> W2d ; [32,1056): conv_w transpose -> Wfb ; [1056,1568): w1/w2/w3 cvt.
__global__ __launch_bounds__(256) void prep_all(
    const float* __restrict__ bbox, const float* __restrict__ conv_w,
    const float* __restrict__ w1, const float* __restrict__ w2, const float* __restrict__ w3,
    unsigned short* __restrict__ W2d, unsigned short* __restrict__ Wfb,
    unsigned short* __restrict__ o1, unsigned short* __restrict__ o2,
    unsigned short* __restrict__ o3)
{
  __shared__ __align__(16) char psm[18504];
  int tid = threadIdx.x;
  int bx = blockIdx.x;

  if (bx < 32) {                       // ---- ROI weights + W2d, b = bx
    int b = bx;
    float* wyS = (float*)psm;          // 1056 f32
    float* wxS = wyS + 1056;           // 1056 f32
    for (int t = tid; t < 352; t += 256) {
      int n = t / 22, i = t - n * 22;
      float4 bb = ((const float4*)bbox)[b*16 + n];
      float x1 = bb.x * SCALE_, y1 = bb.y * SCALE_;
      float x2 = (bb.x + bb.z) * SCALE_, y2 = (bb.y + bb.w) * SCALE_;
      float bw = (x2 - x1) / 3.f, bh = (y2 - y1) / 3.f;
      float area = fmaxf(bw * bh, 0.f);
      float inv = area > 0.f ? 1.f / fmaxf(area, 1e-12f) : 0.f;
      float fi = (float)i;
#pragma unroll
      for (int q = 0; q < 3; ++q) {
        float sy = y1 + q * bh;
        wyS[n*66 + q*22 + i] = hat_int(sy + bh - fi) - hat_int(sy - fi);
        float sx = x1 + q * bw;
        wxS[n*66 + q*22 + i] = (hat_int(sx + bw - fi) - hat_int(sx - fi)) * inv;
      }
    }
    __syncthreads();
    if (tid < 144) {
      int n = tid / 9, qp = tid - n*9, q = qp / 3, p = qp - q*3;
      const float* wyp = wyS + n*66 + q*22;
      const float* wxp = wxS + n*66 + p*22;
      unsigned short* out = W2d + ((size_t)b*144 + tid) * 512;
      for (int h = 0; h < 22; ++h) {
        float yv = wyp[h];
        int kb = h * 22;
#pragma unroll
        for (int w = 0; w < 22; w += 2)
          *(unsigned*)&out[kb + w] = pk_bf16(yv * wxp[w], yv * wxp[w+1]);
      }
#pragma unroll
      for (int k = 484; k < 512; k += 2) *(unsigned*)&out[k] = 0u;
    }
  } else if (bx < 1056) {              // ---- convw_t, o = bx - 32
    int o = bx - 32;
    unsigned short (*T)[1028] = (unsigned short(*)[1028])psm;
    const float4* src = (const float4*)(conv_w + (size_t)o * 9216);
#pragma unroll
    for (int it = 0; it < 9; ++it) {
      int i = tid + it * 256;
      float4 v = src[i];
      int e = i * 4;
      { int c = e / 9,     qp = e - c*9;             T[qp][c] = (unsigned short)f2bf(v.x); }
      { int ee = e+1; int c = ee / 9, qp = ee - c*9; T[qp][c] = (unsigned short)f2bf(v.y); }
      { int ee = e+2; int c = ee / 9, qp = ee - c*9; T[qp][c] = (unsigned short)f2bf(v.z); }
      { int ee = e+3; int c = ee / 9, qp = ee - c*9; T[qp][c] = (unsigned short)f2bf(v.w); }
    }
    __syncthreads();
    unsigned short* dst = Wfb + (size_t)o * 9216;
#pragma unroll
    for (int qp = 0; qp < 9; ++qp) {
      uint2 w = *(const uint2*)&T[qp][tid * 4];
      ((uint2*)(dst + qp * 1024))[tid] = w;
    }
  } else {                             // ---- cvt3 (w1,w2,w3)
    int i = (bx - 1056) * 256 + tid;   // [0, 131072)
    const float* src; unsigned short* dst; int g;
    if (i < 65536)      { src = w1; dst = o1; g = i; }
    else if (i < 98304) { src = w2; dst = o2; g = i - 65536; }
    else                { src = w3; dst = o3; g = i - 98304; }
    float4 a = ((const float4*)src)[2*g];
    float4 b = ((const float4*)src)[2*g + 1];
    uint4 pk;
    pk.x = pk_bf16(a.x, a.y); pk.y = pk_bf16(a.z, a.w);
    pk.z = pk_bf16(b.x, b.y); pk.w = pk_bf16(b.z, b.w);
    ((uint4*)dst)[g] = pk;
  }
}

// ================ K2: pooling GEMM (R4-proven). X[(b,n)][qp*1024+c] = W2d[b] . feat[b]^T
__global__ __launch_bounds__(384) void pool_gemm(const float* __restrict__ feat,
                                                 const unsigned short* __restrict__ W2d,
                                                 unsigned short* __restrict__ X) {
  __shared__ __align__(16) unsigned short Bs[64 * 72];   // 9216 B
  int tid = threadIdx.x;
  int nch = blockIdx.x, b = blockIdx.y;
  int lane = tid & 63, wid = tid >> 6;
  int wm = wid >> 1, wn = wid & 1;
  int l15 = lane & 15, kg = lane >> 4;
  const unsigned short* w2b = W2d + (size_t)b * 144 * 512;
  const float* fb = feat + ((size_t)b * C_ + (size_t)nch * 64) * 484;
  f32x4 acc[3][2] = {};

  int c0 = tid >> 4,        f40 = tid & 15;
  int i1 = tid + 384;  int c1 = i1 >> 4, f41 = i1 & 15;
  int i2 = tid + 768;  bool has2 = i2 < 1024; int c2 = i2 >> 4, f42 = i2 & 15;
  float4 bR0, bR1, bR2;

#define LOADB(s) do { \
    bR0 = (((s) < 7 || f40 <= 8) ? *(const float4*)(fb + (size_t)c0*484 + (s)*64 + f40*4) : make_float4(0,0,0,0)); \
    bR1 = (((s) < 7 || f41 <= 8) ? *(const float4*)(fb + (size_t)c1*484 + (s)*64 + f41*4) : make_float4(0,0,0,0)); \
    if (has2) bR2 = (((s) < 7 || f42 <= 8) ? *(const float4*)(fb + (size_t)c2*484 + (s)*64 + f42*4) : make_float4(0,0,0,0)); \
  } while (0)

  LOADB(0);
#pragma unroll
  for (int s = 0; s < 8; ++s) {
    __syncthreads();
    {
      uint2 p0; p0.x = pk_bf16(bR0.x, bR0.y); p0.y = pk_bf16(bR0.z, bR0.w);
      *(uint2*)&Bs[c0*72 + f40*4] = p0;
      uint2 p1; p1.x = pk_bf16(bR1.x, bR1.y); p1.y = pk_bf16(bR1.z, bR1.w);
      *(uint2*)&Bs[c1*72 + f41*4] = p1;
      if (has2) {
        uint2 p2; p2.x = pk_bf16(bR2.x, bR2.y); p2.y = pk_bf16(bR2.z, bR2.w);
        *(uint2*)&Bs[c2*72 + f42*4] = p2;
      }
    }
    if (s < 7) LOADB(s + 1);               // T14 prefetch
    __syncthreads();

    bf16x8 af[3][2], bf[2][2];
#pragma unroll
    for (int fm = 0; fm < 3; ++fm)
#pragma unroll
      for (int kk = 0; kk < 2; ++kk)
        af[fm][kk] = *(const bf16x8*)(w2b + (size_t)(wm*48 + fm*16 + l15) * 512 + s*64 + kk*32 + kg*8);
#pragma unroll
    for (int fn = 0; fn < 2; ++fn)
#pragma unroll
      for (int kk = 0; kk < 2; ++kk)
        bf[fn][kk] = *(const bf16x8*)&Bs[(wn*32 + fn*16 + l15) * 72 + kk*32 + kg*8];
#pragma unroll
    for (int fm = 0; fm < 3; ++fm)
#pragma unroll
      for (int fn = 0; fn < 2; ++fn) {
        acc[fm][fn] = __builtin_amdgcn_mfma_f32_16x16x32_bf16(af[fm][0], bf[fn][0], acc[fm][fn], 0, 0, 0);
        acc[fm][fn] = __builtin_amdgcn_mfma_f32_16x16x32_bf16(af[fm][1], bf[fn][1], acc[fm][fn], 0, 0, 0);
      }
  }
#undef LOADB

#pragma unroll
  for (int fm = 0; fm < 3; ++fm)
#pragma unroll
    for (int r = 0; r < 4; ++r) {
      int m = wm*48 + fm*16 + kg*4 + r;
      int n = m / 9, qp = m - n*9;
      size_t base = ((size_t)(b*16 + n)) * KCONV + (size_t)qp * 1024 + (size_t)nch * 64;
#pragma unroll
      for (int fn = 0; fn < 2; ++fn)
        X[base + wn*32 + fn*16 + l15] = (unsigned short)f2bf(acc[fm][fn][r]);
    }
}

// ================ K3: 128x128 NT GEMM, glds16 + dbuf + XOR swizzle, split-K partials (proven)
__global__ __launch_bounds__(256) void gemm128(const unsigned short* __restrict__ A,
                                               const unsigned short* __restrict__ Bm,
                                               float* __restrict__ Cp,
                                               int M, int N, int K, int kChunk) {
  __shared__ __align__(16) unsigned short As[2][4096];
  __shared__ __align__(16) unsigned short Bs[2][4096];
  int tid = threadIdx.x;
  int lane = tid & 63, wid = tid >> 6;
  int wm = wid >> 1, wn = wid & 1;
  int l15 = lane & 15, kg = lane >> 4;
  int nt = blockIdx.x, mt = blockIdx.y, z = blockIdx.z;
  int kbeg = z * kChunk;
  int steps = kChunk / 32;

  int row0 = tid >> 2, row1 = 64 + row0;
  int slot = tid & 3;
  int s0 = slot ^ ((row0 >> 1) & 3);
  int s1 = slot ^ ((row1 >> 1) & 3);
  const unsigned short* ga0 = A  + (size_t)(mt*128 + row0) * K + kbeg + s0*8;
  const unsigned short* ga1 = A  + (size_t)(mt*128 + row1) * K + kbeg + s1*8;
  const unsigned short* gb0 = Bm + (size_t)(nt*128 + row0) * K + kbeg + s0*8;
  const unsigned short* gb1 = Bm + (size_t)(nt*128 + row1) * K + kbeg + s1*8;
  int wbyte = wid * 1024;

  f32x4 acc[4][4] = {};
  int cur = 0;

#define ISSUE(buf, s) do { int ko = (s) * 32; \
    glds16(ga0 + ko, (char*)&As[(buf)][0] + wbyte); \
    glds16(ga1 + ko, (char*)&As[(buf)][0] + 4096 + wbyte); \
    glds16(gb0 + ko, (char*)&Bs[(buf)][0] + wbyte); \
    glds16(gb1 + ko, (char*)&Bs[(buf)][0] + 4096 + wbyte); } while (0)

  ISSUE(0, 0);
  for (int s = 0; s < steps; ++s) {
    __syncthreads();
    if (s + 1 < steps) ISSUE(cur ^ 1, s + 1);
    bf16x8 af[4], bfr[4];
#pragma unroll
    for (int fm = 0; fm < 4; ++fm) {
      int fr = wm*64 + fm*16 + l15;
      af[fm] = *(const bf16x8*)&As[cur][fr*32 + ((kg ^ ((fr >> 1) & 3)) << 3)];
    }
#pragma unroll
    for (int fn = 0; fn < 4; ++fn) {
      int fr = wn*64 + fn*16 + l15;
      bfr[fn] = *(const bf16x8*)&Bs[cur][fr*32 + ((kg ^ ((fr >> 1) & 3)) << 3)];
    }
#pragma unroll
    for (int fm = 0; fm < 4; ++fm)
#pragma unroll
      for (int fn = 0; fn < 4; ++fn)
        acc[fm][fn] = __builtin_amdgcn_mfma_f32_16x16x32_bf16(af[fm], bfr[fn], acc[fm][fn], 0, 0, 0);
    cur ^= 1;
  }
#undef ISSUE

  float* cp = Cp + ((size_t)z * M + (size_t)mt * 128) * N + (size_t)nt * 128;
#pragma unroll
  for (int fm = 0; fm < 4; ++fm)
#pragma unroll
    for (int fn = 0; fn < 4; ++fn)
#pragma unroll
      for (int r = 0; r < 4; ++r) {
        int row = wm*64 + fm*16 + kg*4 + r;
        int col = wn*64 + fn*16 + l15;
        cp[(size_t)row * N + col] = acc[fm][fn][r];
      }
}

// ================ K4: parallel split-K reduce + BN/ReLU epilogue for conv (proven, MODE 0 only)
__global__ __launch_bounds__(256) void epi0(const float* __restrict__ Cp, int SK, int MN4,
                                            const float* __restrict__ bias,
                                            const float* __restrict__ g,
                                            const float* __restrict__ be,
                                            const float* __restrict__ mu,
                                            const float* __restrict__ var,
                                            unsigned short* __restrict__ outb) {
  int i = blockIdx.x * 256 + threadIdx.x;
  if (i >= MN4) return;
  float4 s = ((const float4*)Cp)[i];
  for (int z = 1; z < SK; ++z) {
    float4 t = ((const float4*)Cp)[(size_t)z * MN4 + i];
    s.x += t.x; s.y += t.y; s.z += t.z; s.w += t.w;
  }
  int n0 = (i * 4) & 1023;
  float v[4] = {s.x, s.y, s.z, s.w};
  float o[4];
#pragma unroll
  for (int j = 0; j < 4; ++j) {
    int n = n0 + j;
    float sc = g[n] * rsqrtf(var[n] + EPS_);
    o[j] = fmaxf((v[j] + bias[n] - mu[n]) * sc + be[n], 0.f);
  }
  uint2 pk; pk.x = pk_bf16(o[0], o[1]); pk.y = pk_bf16(o[2], o[3]);
  *(uint2*)&outb[(size_t)i * 4] = pk;
}

// ================ K5: MLP 64x64 NT GEMM, FULL K (no split-K), fused epilogue.
// MODE 1: bias+ReLU -> bf16 ; MODE 2: bias -> fp32. M=N=512, grid (8,8).
template<int MODE>
__global__ __launch_bounds__(256) void gemm_full(const unsigned short* __restrict__ A,
                                                 const unsigned short* __restrict__ Bm,
                                                 int K,
                                                 const float* __restrict__ bias,
                                                 unsigned short* __restrict__ outb,
                                                 float* __restrict__ outf) {
  __shared__ __align__(16) unsigned short As[64][40];
  __shared__ __align__(16) unsigned short Bs[64][40];
  int tid = threadIdx.x;
  int lane = tid & 63, wid = tid >> 6;
  int wm = wid >> 1, wn = wid & 1;
  int l15 = lane & 15, kg = lane >> 4;
  int nt = blockIdx.x, mt = blockIdx.y;
  int srow = tid >> 2, sseg = tid & 3;
  const unsigned short* aG = A  + (size_t)(mt*64 + srow) * K + sseg * 8;
  const unsigned short* bG = Bm + (size_t)(nt*64 + srow) * K + sseg * 8;
  f32x4 acc[2][2] = {};

  for (int k0 = 0; k0 < K; k0 += 32) {
    uint4 av = *(const uint4*)(aG + k0);
    uint4 bv = *(const uint4*)(bG + k0);
    __syncthreads();
    *(uint4*)&As[srow][sseg*8] = av;
    *(uint4*)&Bs[srow][sseg*8] = bv;
    __syncthreads();
    bf16x8 a0 = *(const bf16x8*)&As[wm*32 +      l15][kg*8];
    bf16x8 a1 = *(const bf16x8*)&As[wm*32 + 16 + l15][kg*8];
    bf16x8 b0 = *(const bf16x8*)&Bs[wn*32 +      l15][kg*8];
    bf16x8 b1 = *(const bf16x8*)&Bs[wn*32 + 16 + l15][kg*8];
    acc[0][0] = __builtin_amdgcn_mfma_f32_16x16x32_bf16(a0, b0, acc[0][0], 0, 0, 0);
    acc[0][1] = __builtin_amdgcn_mfma_f32_16x16x32_bf16(a0, b1, acc[0][1], 0, 0, 0);
    acc[1][0] = __builtin_amdgcn_mfma_f32_16x16x32_bf16(a1, b0, acc[1][0], 0, 0, 0);
    acc[1][1] = __builtin_amdgcn_mfma_f32_16x16x32_bf16(a1, b1, acc[1][1], 0, 0, 0);
  }

#pragma unroll
  for (int fm = 0; fm < 2; ++fm)
#pragma unroll
    for (int fn = 0; fn < 2; ++fn)
#pragma unroll
      for (int r = 0; r < 4; ++r) {
        int grow = mt*64 + wm*32 + fm*16 + kg*4 + r;
        int gcol = nt*64 + wn*32 + fn*16 + l15;
        float v = acc[fm][fn][r] + bias[gcol];
        if (MODE == 1)
          outb[(size_t)grow * 512 + gcol] = (unsigned short)f2bf(fmaxf(v, 0.f));
        else
          outf[(size_t)grow * 512 + gcol] = v;
      }
}

extern "C" void kernel_launch(void* const* d_in, const int* in_sizes, int n_in,
                              void* d_out, int out_size, void* d_ws, size_t ws_size,
                              hipStream_t stream) {
  const float* feat   = (const float*)d_in[0];
  const float* bbox   = (const float*)d_in[1];
  const float* conv_w = (const float*)d_in[2];
  const float* conv_b = (const float*)d_in[3];
  const float* gamma  = (const float*)d_in[4];
  const float* beta   = (const float*)d_in[5];
  const float* mean   = (const float*)d_in[6];
  const float* var    = (const float*)d_in[7];
  const float* w1     = (const float*)d_in[8];
  const float* b1     = (const float*)d_in[9];
  const float* w2     = (const float*)d_in[10];
  const float* b2     = (const float*)d_in[11];
  const float* w3     = (const float*)d_in[12];
  const float* b3     = (const float*)d_in[13];

  char* ws = (char*)d_ws;
  unsigned short* W2d = (unsigned short*)(ws);              //  4718592 B [32][144][512]
  unsigned short* Xb  = (unsigned short*)(ws + 4718592);    //  9437184 B [512][9216]
  unsigned short* Wfb = (unsigned short*)(ws + 14155776);   // 18874368 B [1024][9216] (qp-major)
  unsigned short* w1b = (unsigned short*)(ws + 33030144);   //  1048576 B
  unsigned short* w2b = (unsigned short*)(ws + 34078720);   //   524288 B
  unsigned short* w3b = (unsigned short*)(ws + 34603008);   //   524288 B
  float*          part= (float*)(ws + 35127296);            // 16777216 B [8][512][1024] f32
  unsigned short* H0  = (unsigned short*)(ws + 51904512);   //  1048576 B
  unsigned short* H1  = (unsigned short*)(ws + 52953088);   //   524288 B
  unsigned short* H2  = (unsigned short*)(ws + 53477376);   //   524288 B (total 54001664 B)

  // 1: all preprocessing (ROI->W2d, conv_w transpose, MLP weight cvt)
  prep_all<<<1568, 256, 0, stream>>>(bbox, conv_w, w1, w2, w3, W2d, Wfb, w1b, w2b, w3b);

  // 2: pooling GEMM: per-b, M=144, N=1024 (16 chunks of 64), K=512
  pool_gemm<<<dim3(16, 32), 384, 0, stream>>>(feat, W2d, Xb);

  // 3: conv GEMM: [512,9216] x [1024,9216]^T, 128^2 tiles, SK=8 -> 256 blocks
  gemm128<<<dim3(8, 4, 8), 256, 0, stream>>>(Xb, Wfb, part, 512, 1024, 9216, 1152);
  // 4: parallel SK=8 reduce + BN + ReLU -> H0
  epi0<<<512, 256, 0, stream>>>(part, 8, 131072, conv_b, gamma, beta, mean, var, H0);

  // 5-7: MLP, full-K fused-epilogue GEMMs (no split-K, no separate epi)
  gemm_full<1><<<dim3(8, 8), 256, 0, stream>>>(H0, w1b, 1024, b1, H1, nullptr);
  gemm_full<1><<<dim3(8, 8), 256, 0, stream>>>(H1, w2b, 512,  b2, H2, nullptr);
  gemm_full<2><<<dim3(8, 8), 256, 0, stream>>>(H2, w3b, 512,  b3, nullptr, (float*)d_out);
}

// Round 10
// 123.066 us; speedup vs baseline: 4.0064x; 1.0111x over previous
//
#include <hip/hip_runtime.h>
#include <hip/hip_bf16.h>

#define B_    32
#define NBB_  16
#define C_    1024
#define NROI  512
#define KCONV 9216
#define SCALE_ (1.0f/16.0f)
#define EPS_  1e-5f

using f32x4  = __attribute__((ext_vector_type(4))) float;
using bf16x8 = __attribute__((ext_vector_type(8))) short;

__device__ __forceinline__ unsigned f2bf(float f) {
  union { float f; unsigned u; } x; x.f = f;
  unsigned r = x.u + 0x7fffu + ((x.u >> 16) & 1u);   // RNE
  return r >> 16;
}

__device__ __forceinline__ unsigned pk_bf16(float lo, float hi) {
  __hip_bfloat162 h = __float22bfloat162_rn(make_float2(lo, hi));
  return *reinterpret_cast<unsigned*>(&h);
}

__device__ __forceinline__ float hat_int(float t) {
  t = fminf(fmaxf(t, -1.f), 1.f);
  return t + 0.5f - 0.5f * t * fabsf(t);
}

__device__ __forceinline__ void glds16(const void* g, void* l) {
  __builtin_amdgcn_global_load_lds((const __attribute__((address_space(1))) void*)g,
                                   (__attribute__((address_space(3))) void*)l, 16, 0, 0);
}

// ================ K1: ALL preprocessing, one launch. c-major K-order -> conv_w cvt is LINEAR.
// blocks [0,32): ROI weights -> W2d ; [32,4640): conv_w linear cvt -> Wfb ; [4640,5152): w1/w2/w3 cvt.
__global__ __launch_bounds__(256) void prep_all(
    const float* __restrict__ bbox, const float* __restrict__ conv_w,
    const float* __restrict__ w1, const float* __restrict__ w2, const float* __restrict__ w3,
    unsigned short* __restrict__ W2d, unsigned short* __restrict__ Wfb,
    unsigned short* __restrict__ o1, unsigned short* __restrict__ o2,
    unsigned short* __restrict__ o3)
{
  __shared__ __align__(16) float psm[2112];
  int tid = threadIdx.x;
  int bx = blockIdx.x;

  if (bx >= 32 && bx < 4640) {         // ---- conv_w linear cvt (dominant branch first in code path)
    int g = (bx - 32) * 256 + tid;     // [0, 1179648) groups of 8 floats
    float4 a = ((const float4*)conv_w)[2*g];
    float4 b = ((const float4*)conv_w)[2*g + 1];
    uint4 pk;
    pk.x = pk_bf16(a.x, a.y); pk.y = pk_bf16(a.z, a.w);
    pk.z = pk_bf16(b.x, b.y); pk.w = pk_bf16(b.z, b.w);
    ((uint4*)Wfb)[g] = pk;
    return;
  }
  if (bx < 32) {                       // ---- ROI weights + W2d, b = bx
    int b = bx;
    float* wyS = psm;                  // 1056 f32
    float* wxS = psm + 1056;           // 1056 f32
    for (int t = tid; t < 352; t += 256) {
      int n = t / 22, i = t - n * 22;
      float4 bb = ((const float4*)bbox)[b*16 + n];
      float x1 = bb.x * SCALE_, y1 = bb.y * SCALE_;
      float x2 = (bb.x + bb.z) * SCALE_, y2 = (bb.y + bb.w) * SCALE_;
      float bw = (x2 - x1) / 3.f, bh = (y2 - y1) / 3.f;
      float area = fmaxf(bw * bh, 0.f);
      float inv = area > 0.f ? 1.f / fmaxf(area, 1e-12f) : 0.f;
      float fi = (float)i;
#pragma unroll
      for (int q = 0; q < 3; ++q) {
        float sy = y1 + q * bh;
        wyS[n*66 + q*22 + i] = hat_int(sy + bh - fi) - hat_int(sy - fi);
        float sx = x1 + q * bw;
        wxS[n*66 + q*22 + i] = (hat_int(sx + bw - fi) - hat_int(sx - fi)) * inv;
      }
    }
    __syncthreads();
    if (tid < 144) {
      int n = tid / 9, qp = tid - n*9, q = qp / 3, p = qp - q*3;
      const float* wyp = wyS + n*66 + q*22;
      const float* wxp = wxS + n*66 + p*22;
      unsigned short* out = W2d + ((size_t)b*144 + tid) * 512;
      for (int h = 0; h < 22; ++h) {
        float yv = wyp[h];
        int kb = h * 22;
#pragma unroll
        for (int w = 0; w < 22; w += 2)
          *(unsigned*)&out[kb + w] = pk_bf16(yv * wxp[w], yv * wxp[w+1]);
      }
#pragma unroll
      for (int k = 484; k < 512; k += 2) *(unsigned*)&out[k] = 0u;
    }
  } else {                             // ---- cvt3 (w1,w2,w3)
    int i = (bx - 4640) * 256 + tid;   // [0, 131072)
    const float* src; unsigned short* dst; int g;
    if (i < 65536)      { src = w1; dst = o1; g = i; }
    else if (i < 98304) { src = w2; dst = o2; g = i - 65536; }
    else                { src = w3; dst = o3; g = i - 98304; }
    float4 a = ((const float4*)src)[2*g];
    float4 b = ((const float4*)src)[2*g + 1];
    uint4 pk;
    pk.x = pk_bf16(a.x, a.y); pk.y = pk_bf16(a.z, a.w);
    pk.z = pk_bf16(b.x, b.y); pk.w = pk_bf16(b.z, b.w);
    ((uint4*)dst)[g] = pk;
  }
}

// ================ K2: pooling GEMM (R4-proven MFMA body) + LDS-staged c-major coalesced X-write.
// Block (nch, b); 384 thr = 6 waves (3wm x 2wn). M=144, N=64, K=512(484).
// X layout: [roi][k = c*9 + qp]  (c-major, matches conv_w natural flatten).
__global__ __launch_bounds__(384) void pool_gemm(const float* __restrict__ feat,
                                                 const unsigned short* __restrict__ W2d,
                                                 unsigned short* __restrict__ X) {
  __shared__ __align__(16) unsigned short Bs[64 * 72];   // 9216 B
  __shared__ __align__(16) unsigned short Xs[16][580];   // 18560 B (576 data + pad)
  int tid = threadIdx.x;
  int nch = blockIdx.x, b = blockIdx.y;
  int lane = tid & 63, wid = tid >> 6;
  int wm = wid >> 1, wn = wid & 1;
  int l15 = lane & 15, kg = lane >> 4;
  const unsigned short* w2b = W2d + (size_t)b * 144 * 512;
  const float* fb = feat + ((size_t)b * C_ + (size_t)nch * 64) * 484;
  f32x4 acc[3][2] = {};

  int c0 = tid >> 4,        f40 = tid & 15;
  int i1 = tid + 384;  int c1 = i1 >> 4, f41 = i1 & 15;
  int i2 = tid + 768;  bool has2 = i2 < 1024; int c2 = i2 >> 4, f42 = i2 & 15;
  float4 bR0, bR1, bR2;

#define LOADB(s) do { \
    bR0 = (((s) < 7 || f40 <= 8) ? *(const float4*)(fb + (size_t)c0*484 + (s)*64 + f40*4) : make_float4(0,0,0,0)); \
    bR1 = (((s) < 7 || f41 <= 8) ? *(const float4*)(fb + (size_t)c1*484 + (s)*64 + f41*4) : make_float4(0,0,0,0)); \
    if (has2) bR2 = (((s) < 7 || f42 <= 8) ? *(const float4*)(fb + (size_t)c2*484 + (s)*64 + f42*4) : make_float4(0,0,0,0)); \
  } while (0)

  LOADB(0);
#pragma unroll
  for (int s = 0; s < 8; ++s) {
    __syncthreads();
    {
      uint2 p0; p0.x = pk_bf16(bR0.x, bR0.y); p0.y = pk_bf16(bR0.z, bR0.w);
      *(uint2*)&Bs[c0*72 + f40*4] = p0;
      uint2 p1; p1.x = pk_bf16(bR1.x, bR1.y); p1.y = pk_bf16(bR1.z, bR1.w);
      *(uint2*)&Bs[c1*72 + f41*4] = p1;
      if (has2) {
        uint2 p2; p2.x = pk_bf16(bR2.x, bR2.y); p2.y = pk_bf16(bR2.z, bR2.w);
        *(uint2*)&Bs[c2*72 + f42*4] = p2;
      }
    }
    if (s < 7) LOADB(s + 1);               // T14 prefetch
    __syncthreads();

    bf16x8 af[3][2], bf[2][2];
#pragma unroll
    for (int fm = 0; fm < 3; ++fm)
#pragma unroll
      for (int kk = 0; kk < 2; ++kk)
        af[fm][kk] = *(const bf16x8*)(w2b + (size_t)(wm*48 + fm*16 + l15) * 512 + s*64 + kk*32 + kg*8);
#pragma unroll
    for (int fn = 0; fn < 2; ++fn)
#pragma unroll
      for (int kk = 0; kk < 2; ++kk)
        bf[fn][kk] = *(const bf16x8*)&Bs[(wn*32 + fn*16 + l15) * 72 + kk*32 + kg*8];
#pragma unroll
    for (int fm = 0; fm < 3; ++fm)
#pragma unroll
      for (int fn = 0; fn < 2; ++fn) {
        acc[fm][fn] = __builtin_amdgcn_mfma_f32_16x16x32_bf16(af[fm][0], bf[fn][0], acc[fm][fn], 0, 0, 0);
        acc[fm][fn] = __builtin_amdgcn_mfma_f32_16x16x32_bf16(af[fm][1], bf[fn][1], acc[fm][fn], 0, 0, 0);
      }
  }
#undef LOADB

  // acc -> LDS scatter (c-major within the block's 576-elem span), then coalesced u32 store.
#pragma unroll
  for (int fm = 0; fm < 3; ++fm)
#pragma unroll
    for (int r = 0; r < 4; ++r) {
      int m = wm*48 + fm*16 + kg*4 + r;
      int n = m / 9, qp = m - n*9;
#pragma unroll
      for (int fn = 0; fn < 2; ++fn) {
        int c = wn*32 + fn*16 + l15;
        Xs[n][c*9 + qp] = (unsigned short)f2bf(acc[fm][fn][r]);
      }
    }
  __syncthreads();
  // 16 rois x 576 u16 = 4608 u32; X span per roi is contiguous: [roi][nch*576 .. +576)
  for (int idx = tid; idx < 4608; idx += 384) {
    int n = idx / 288, j = idx - n * 288;
    *(unsigned*)&X[((size_t)(b*16 + n)) * KCONV + (size_t)nch * 576 + j*2] =
        *(const unsigned*)&Xs[n][j*2];
  }
}

// ================ K3: 128x128 NT GEMM, glds16 + dbuf + XOR swizzle, split-K partials (proven)
__global__ __launch_bounds__(256) void gemm128(const unsigned short* __restrict__ A,
                                               const unsigned short* __restrict__ Bm,
                                               float* __restrict__ Cp,
                                               int M, int N, int K, int kChunk) {
  __shared__ __align__(16) unsigned short As[2][4096];
  __shared__ __align__(16) unsigned short Bs[2][4096];
  int tid = threadIdx.x;
  int lane = tid & 63, wid = tid >> 6;
  int wm = wid >> 1, wn = wid & 1;
  int l15 = lane & 15, kg = lane >> 4;
  int nt = blockIdx.x, mt = blockIdx.y, z = blockIdx.z;
  int kbeg = z * kChunk;
  int steps = kChunk / 32;

  int row0 = tid >> 2, row1 = 64 + row0;
  int slot = tid & 3;
  int s0 = slot ^ ((row0 >> 1) & 3);
  int s1 = slot ^ ((row1 >> 1) & 3);
  const unsigned short* ga0 = A  + (size_t)(mt*128 + row0) * K + kbeg + s0*8;
  const unsigned short* ga1 = A  + (size_t)(mt*128 + row1) * K + kbeg + s1*8;
  const unsigned short* gb0 = Bm + (size_t)(nt*128 + row0) * K + kbeg + s0*8;
  const unsigned short* gb1 = Bm + (size_t)(nt*128 + row1) * K + kbeg + s1*8;
  int wbyte = wid * 1024;

  f32x4 acc[4][4] = {};
  int cur = 0;

#define ISSUE(buf, s) do { int ko = (s) * 32; \
    glds16(ga0 + ko, (char*)&As[(buf)][0] + wbyte); \
    glds16(ga1 + ko, (char*)&As[(buf)][0] + 4096 + wbyte); \
    glds16(gb0 + ko, (char*)&Bs[(buf)][0] + wbyte); \
    glds16(gb1 + ko, (char*)&Bs[(buf)][0] + 4096 + wbyte); } while (0)

  ISSUE(0, 0);
  for (int s = 0; s < steps; ++s) {
    __syncthreads();
    if (s + 1 < steps) ISSUE(cur ^ 1, s + 1);
    bf16x8 af[4], bfr[4];
#pragma unroll
    for (int fm = 0; fm < 4; ++fm) {
      int fr = wm*64 + fm*16 + l15;
      af[fm] = *(const bf16x8*)&As[cur][fr*32 + ((kg ^ ((fr >> 1) & 3)) << 3)];
    }
#pragma unroll
    for (int fn = 0; fn < 4; ++fn) {
      int fr = wn*64 + fn*16 + l15;
      bfr[fn] = *(const bf16x8*)&Bs[cur][fr*32 + ((kg ^ ((fr >> 1) & 3)) << 3)];
    }
#pragma unroll
    for (int fm = 0; fm < 4; ++fm)
#pragma unroll
      for (int fn = 0; fn < 4; ++fn)
        acc[fm][fn] = __builtin_amdgcn_mfma_f32_16x16x32_bf16(af[fm], bfr[fn], acc[fm][fn], 0, 0, 0);
    cur ^= 1;
  }
#undef ISSUE

  float* cp = Cp + ((size_t)z * M + (size_t)mt * 128) * N + (size_t)nt * 128;
#pragma unroll
  for (int fm = 0; fm < 4; ++fm)
#pragma unroll
    for (int fn = 0; fn < 4; ++fn)
#pragma unroll
      for (int r = 0; r < 4; ++r) {
        int row = wm*64 + fm*16 + kg*4 + r;
        int col = wn*64 + fn*16 + l15;
        cp[(size_t)row * N + col] = acc[fm][fn][r];
      }
}

// ================ K4: parallel split-K reduce + BN/ReLU epilogue (proven)
__global__ __launch_bounds__(256) void epi0(const float* __restrict__ Cp, int SK, int MN4,
                                            const float* __restrict__ bias,
                                            const float* __restrict__ g,
                                            const float* __restrict__ be,
                                            const float* __restrict__ mu,
                                            const float* __restrict__ var,
                                            unsigned short* __restrict__ outb) {
  int i = blockIdx.x * 256 + threadIdx.x;
  if (i >= MN4) return;
  float4 s = ((const float4*)Cp)[i];
  for (int z = 1; z < SK; ++z) {
    float4 t = ((const float4*)Cp)[(size_t)z * MN4 + i];
    s.x += t.x; s.y += t.y; s.z += t.z; s.w += t.w;
  }
  int n0 = (i * 4) & 1023;
  float v[4] = {s.x, s.y, s.z, s.w};
  float o[4];
#pragma unroll
  for (int j = 0; j < 4; ++j) {
    int n = n0 + j;
    float sc = g[n] * rsqrtf(var[n] + EPS_);
    o[j] = fmaxf((v[j] + bias[n] - mu[n]) * sc + be[n], 0.f);
  }
  uint2 pk; pk.x = pk_bf16(o[0], o[1]); pk.y = pk_bf16(o[2], o[3]);
  *(uint2*)&outb[(size_t)i * 4] = pk;
}

// ================ K5: MLP 64x64 NT GEMM, FULL K, fused epilogue (R9-proven).
template<int MODE>
__global__ __launch_bounds__(256) void gemm_full(const unsigned short* __restrict__ A,
                                                 const unsigned short* __restrict__ Bm,
                                                 int K,
                                                 const float* __restrict__ bias,
                                                 unsigned short* __restrict__ outb,
                                                 float* __restrict__ outf) {
  __shared__ __align__(16) unsigned short As[64][40];
  __shared__ __align__(16) unsigned short Bs[64][40];
  int tid = threadIdx.x;
  int lane = tid & 63, wid = tid >> 6;
  int wm = wid >> 1, wn = wid & 1;
  int l15 = lane & 15, kg = lane >> 4;
  int nt = blockIdx.x, mt = blockIdx.y;
  int srow = tid >> 2, sseg = tid & 3;
  const unsigned short* aG = A  + (size_t)(mt*64 + srow) * K + sseg * 8;
  const unsigned short* bG = Bm + (size_t)(nt*64 + srow) * K + sseg * 8;
  f32x4 acc[2][2] = {};

  for (int k0 = 0; k0 < K; k0 += 32) {
    uint4 av = *(const uint4*)(aG + k0);
    uint4 bv = *(const uint4*)(bG + k0);
    __syncthreads();
    *(uint4*)&As[srow][sseg*8] = av;
    *(uint4*)&Bs[srow][sseg*8] = bv;
    __syncthreads();
    bf16x8 a0 = *(const bf16x8*)&As[wm*32 +      l15][kg*8];
    bf16x8 a1 = *(const bf16x8*)&As[wm*32 + 16 + l15][kg*8];
    bf16x8 b0 = *(const bf16x8*)&Bs[wn*32 +      l15][kg*8];
    bf16x8 b1 = *(const bf16x8*)&Bs[wn*32 + 16 + l15][kg*8];
    acc[0][0] = __builtin_amdgcn_mfma_f32_16x16x32_bf16(a0, b0, acc[0][0], 0, 0, 0);
    acc[0][1] = __builtin_amdgcn_mfma_f32_16x16x32_bf16(a0, b1, acc[0][1], 0, 0, 0);
    acc[1][0] = __builtin_amdgcn_mfma_f32_16x16x32_bf16(a1, b0, acc[1][0], 0, 0, 0);
    acc[1][1] = __builtin_amdgcn_mfma_f32_16x16x32_bf16(a1, b1, acc[1][1], 0, 0, 0);
  }

#pragma unroll
  for (int fm = 0; fm < 2; ++fm)
#pragma unroll
    for (int fn = 0; fn < 2; ++fn)
#pragma unroll
      for (int r = 0; r < 4; ++r) {
        int grow = mt*64 + wm*32 + fm*16 + kg*4 + r;
        int gcol = nt*64 + wn*32 + fn*16 + l15;
        float v = acc[fm][fn][r] + bias[gcol];
        if (MODE == 1)
          outb[(size_t)grow * 512 + gcol] = (unsigned short)f2bf(fmaxf(v, 0.f));
        else
          outf[(size_t)grow * 512 + gcol] = v;
      }
}

extern "C" void kernel_launch(void* const* d_in, const int* in_sizes, int n_in,
                              void* d_out, int out_size, void* d_ws, size_t ws_size,
                              hipStream_t stream) {
  const float* feat   = (const float*)d_in[0];
  const float* bbox   = (const float*)d_in[1];
  const float* conv_w = (const float*)d_in[2];
  const float* conv_b = (const float*)d_in[3];
  const float* gamma  = (const float*)d_in[4];
  const float* beta   = (const float*)d_in[5];
  const float* mean   = (const float*)d_in[6];
  const float* var    = (const float*)d_in[7];
  const float* w1     = (const float*)d_in[8];
  const float* b1     = (const float*)d_in[9];
  const float* w2     = (const float*)d_in[10];
  const float* b2     = (const float*)d_in[11];
  const float* w3     = (const float*)d_in[12];
  const float* b3     = (const float*)d_in[13];

  char* ws = (char*)d_ws;
  unsigned short* W2d = (unsigned short*)(ws);              //  4718592 B [32][144][512]
  unsigned short* Xb  = (unsigned short*)(ws + 4718592);    //  9437184 B [512][9216] c-major
  unsigned short* Wfb = (unsigned short*)(ws + 14155776);   // 18874368 B [1024][9216] c-major (linear cvt)
  unsigned short* w1b = (unsigned short*)(ws + 33030144);   //  1048576 B
  unsigned short* w2b = (unsigned short*)(ws + 34078720);   //   524288 B
  unsigned short* w3b = (unsigned short*)(ws + 34603008);   //   524288 B
  float*          part= (float*)(ws + 35127296);            // 16777216 B [8][512][1024] f32
  unsigned short* H0  = (unsigned short*)(ws + 51904512);   //  1048576 B
  unsigned short* H1  = (unsigned short*)(ws + 52953088);   //   524288 B
  unsigned short* H2  = (unsigned short*)(ws + 53477376);   //   524288 B (total 54001664 B)

  // 1: all preprocessing (ROI->W2d, conv_w LINEAR cvt, MLP weight cvt)
  prep_all<<<5152, 256, 0, stream>>>(bbox, conv_w, w1, w2, w3, W2d, Wfb, w1b, w2b, w3b);

  // 2: pooling GEMM: per-b, M=144, N=1024 (16 chunks of 64), K=512; c-major coalesced X-write
  pool_gemm<<<dim3(16, 32), 384, 0, stream>>>(feat, W2d, Xb);

  // 3: conv GEMM: [512,9216] x [1024,9216]^T, 128^2 tiles, SK=8 -> 256 blocks
  gemm128<<<dim3(8, 4, 8), 256, 0, stream>>>(Xb, Wfb, part, 512, 1024, 9216, 1152);
  // 4: parallel SK=8 reduce + BN + ReLU -> H0
  epi0<<<512, 256, 0, stream>>>(part, 8, 131072, conv_b, gamma, beta, mean, var, H0);

  // 5-7: MLP, full-K fused-epilogue GEMMs
  gemm_full<1><<<dim3(8, 8), 256, 0, stream>>>(H0, w1b, 1024, b1, H1, nullptr);
  gemm_full<1><<<dim3(8, 8), 256, 0, stream>>>(H1, w2b, 512,  b2, H2, nullptr);
  gemm_full<2><<<dim3(8, 8), 256, 0, stream>>>(H2, w3b, 512,  b3, nullptr, (float*)d_out);
}